// Round 6
// baseline (88.289 us; speedup 1.0000x reference)
//
#include <hip/hip_runtime.h>
#include <cstdint>

#define IN_DIM   128
#define OUT_DIM  256
#define NROWS    32768
#define BM       64            // rows per block
#define NSTEPS   16            // K = 4096 = 16 * 256 (BK=256: 8 i-values/step)
#define STR      65            // bf16x8 row stride (64 + 1 pad)

typedef unsigned short u16;
typedef __attribute__((ext_vector_type(8))) __bf16 bf16x8;
typedef __attribute__((ext_vector_type(4))) float  f32x4;

// ---------------------------------------------------------------------------
// Prep: repack fouriercoeffs (2,256,128,16) f32 -> Bpack bf16 [K/8][256][8]
// with k = i*32 + t*16 + g  (t: 0=cos, 1=sin; slot g holds harmonic g+1).
// ---------------------------------------------------------------------------
__global__ __launch_bounds__(256) void kan_prep(const float* __restrict__ C,
                                                u16* __restrict__ Bpack) {
    const int o = threadIdx.x;   // 0..255 output channel
    const int i = blockIdx.x;    // 0..127 input dim
    const int t = blockIdx.y;    // 0=cos, 1=sin
    const float* src = C + (((size_t)(t * OUT_DIM + o) * IN_DIM + i) * 16);
    bf16x8 lo = {}, hi = {};
#pragma unroll
    for (int g = 0; g < 8; ++g) {
        lo[g] = (__bf16)src[g];
        hi[g] = (__bf16)src[8 + g];
    }
    const int ko = i * 4 + t * 2;       // k>>3
    bf16x8* dst = (bf16x8*)Bpack;
    dst[(size_t)ko * OUT_DIM + o]       = lo;   // g = 0..7
    dst[(size_t)(ko + 1) * OUT_DIM + o] = hi;   // g = 8..15
}

// ---------------------------------------------------------------------------
// Fused trig + bf16 MFMA GEMM, v6 = v5 with 2D wave tiling (the ONE change):
//  - wave tile 32x64: wm=wid&1 (row half), wn=wid>>1 (col quarter).
//    A-LDS read amplification drops 8x -> 4x (v5's measured critical path:
//    8192 reads/CU x ~19cy = 81% of wall). B-L2 doubles to nm=2, but the two
//    wm-waves read identical B addresses barrier-synced -> L1 serves pair.
//  - Everything else (gen, 1-barrier dbuf loop, B reg-prefetch, epilogue
//    family, 512 thr, 2 blocks/CU) v5-verbatim.
// ---------------------------------------------------------------------------
__global__ __launch_bounds__(512, 4) void kan_gemm(const float* __restrict__ x,
                                                   const u16* __restrict__ Bpack,
                                                   const float* __restrict__ bias,
                                                   float* __restrict__ out) {
    __shared__ __align__(16) u16 Asm[2][32 * STR * 8];   // 2 x 33280 B

    const int tid  = threadIdx.x;
    const int lane = tid & 63;
    const int wid  = tid >> 6;       // 0..7
    const int lrow = lane & 15;
    const int lk   = lane >> 4;      // 0..3  k-chunk
    const int wm   = wid & 1;        // 0..1  row half (32 rows)
    const int wn   = wid >> 1;       // 0..3  col quarter (64 cols)
    const int m0   = blockIdx.x * BM;

    // trig task mapping: thread -> (row tr, i-sub til), i = kt*8 + til
    const int tr  = tid >> 3;        // 0..63
    const int til = tid & 7;         // 0..7

    const f32x4 vzero = {0.f, 0.f, 0.f, 0.f};
    f32x4 acc[2][4];
#pragma unroll
    for (int a = 0; a < 2; ++a)
#pragma unroll
        for (int b = 0; b < 4; ++b) acc[a][b] = vzero;

    const bf16x8* Bv = (const bf16x8*)Bpack;
    bf16x8* Av0 = (bf16x8*)Asm[0];
    bf16x8* Av1 = (bf16x8*)Asm[1];

    const float* xrow = x + (size_t)(m0 + tr) * IN_DIM + til;
    const int bcol = wn * 64 + lrow;           // + f*16 per fragment

    // ---- harmonic generator (v5 verbatim): 4 ds_write_b128 ----
    auto gen = [&](bf16x8* Av, float xv) {
        float s1, c1;
        __sincosf(xv, &s1, &c1);
        const float t2 = 2.f * c1;
        bf16x8 qc0 = {}, qc1 = {}, qs0 = {}, qs1 = {};
        float cp = c1, sp = s1;                    // harmonic 1
        float cc = t2 * c1 - 1.f, sc = t2 * s1;    // harmonic 2
        qc0[0] = (__bf16)cp;  qs0[0] = (__bf16)sp;
        qc0[1] = (__bf16)cc;  qs0[1] = (__bf16)sc;
#pragma unroll
        for (int g = 3; g <= 16; ++g) {            // Chebyshev: 2 FMA each
            const float cn = t2 * cc - cp;
            const float sn = t2 * sc - sp;
            cp = cc; sp = sc; cc = cn; sc = sn;
            const int idx = g - 1;                 // slot = harmonic-1
            if (idx < 8) { qc0[idx] = (__bf16)cc;      qs0[idx] = (__bf16)sc; }
            else         { qc1[idx - 8] = (__bf16)cc;  qs1[idx - 8] = (__bf16)sc; }
        }
        const int kob = til * 4;   // local ko = til*4 + t*2 + (g>>3)
        Av[(kob + 0) * STR + tr] = qc0;
        Av[(kob + 1) * STR + tr] = qc1;
        Av[(kob + 2) * STR + tr] = qs0;
        Av[(kob + 3) * STR + tr] = qs1;
    };

    // prime B fragments for kt=0, ks=0  (ko_global = lk)
    bf16x8 bg[4];
#pragma unroll
    for (int f = 0; f < 4; ++f)
        bg[f] = Bv[(size_t)lk * OUT_DIM + bcol + f * 16];

    // prologue: gen tile 0, prefetch x for tile 1
    float xn = xrow[8];
    gen(Av0, xrow[0]);
    __syncthreads();

    for (int kt = 0; kt < NSTEPS; ++kt) {
        bf16x8* Avc = (kt & 1) ? Av1 : Av0;
        bf16x8* Avn = (kt & 1) ? Av0 : Av1;

        // generate next A tile (VALU) — interleaves with this tile's MFMAs
        if (kt + 1 < NSTEPS) {
            gen(Avn, xn);
            xn = xrow[((kt + 2) & (NSTEPS - 1)) * 8];
        }

#pragma unroll
        for (int ks = 0; ks < 8; ++ks) {
            // prefetch next ks's B fragments (wraps harmlessly at the end)
            const int ktn = (ks == 7) ? ((kt + 1) & (NSTEPS - 1)) : kt;
            const int ksn = (ks + 1) & 7;
            const size_t kqn = (size_t)(ktn * 32 + ksn * 4 + lk);
            bf16x8 bgn[4];
#pragma unroll
            for (int f = 0; f < 4; ++f)
                bgn[f] = Bv[kqn * OUT_DIM + bcol + f * 16];

            const int kq = ks * 4 + lk;
            bf16x8 af[2];
#pragma unroll
            for (int f = 0; f < 2; ++f)
                af[f] = Avc[kq * STR + wm * 32 + f * 16 + lrow];
#pragma unroll
            for (int fm = 0; fm < 2; ++fm)
#pragma unroll
                for (int fn = 0; fn < 4; ++fn)
                    acc[fm][fn] = __builtin_amdgcn_mfma_f32_16x16x32_bf16(
                        af[fm], bg[fn], acc[fm][fn], 0, 0, 0);
#pragma unroll
            for (int f = 0; f < 4; ++f) bg[f] = bgn[f];
        }
        __syncthreads();
    }

    // ---- epilogue: C[row][col], row=(lane>>4)*4+j, col=lane&15 ----
#pragma unroll
    for (int fn = 0; fn < 4; ++fn) {
        const int col = wn * 64 + fn * 16 + lrow;
        const float bv = bias[col];
#pragma unroll
        for (int fm = 0; fm < 2; ++fm) {
            const int r0 = m0 + wm * 32 + fm * 16 + lk * 4;
            float* op = out + (size_t)r0 * OUT_DIM + col;
#pragma unroll
            for (int j = 0; j < 4; ++j)
                op[(size_t)j * OUT_DIM] = acc[fm][fn][j] + bv;
        }
    }
}

extern "C" void kernel_launch(void* const* d_in, const int* in_sizes, int n_in,
                              void* d_out, int out_size, void* d_ws, size_t ws_size,
                              hipStream_t stream) {
    const float* x    = (const float*)d_in[0];   // (32768, 128) f32
    const float* fc   = (const float*)d_in[1];   // (2, 256, 128, 16) f32
    const float* bias = (const float*)d_in[2];   // (1, 256) f32
    float* out        = (float*)d_out;           // (32768, 256) f32
    u16* Bpack        = (u16*)d_ws;              // 4096*256*2 B = 2 MB scratch

    kan_prep<<<dim3(IN_DIM, 2), OUT_DIM, 0, stream>>>(fc, Bpack);
    kan_gemm<<<dim3(NROWS / BM), 512, 0, stream>>>(x, Bpack, bias, out);
}

// Round 7
// 79.421 us; speedup vs baseline: 1.1117x; 1.1117x over previous
//
#include <hip/hip_runtime.h>
#include <cstdint>

#define IN_DIM   128
#define OUT_DIM  256
#define NROWS    32768
#define BM       64            // rows per block
#define NSTEPS   32            // K = 4096 = 32 * 128 (BK=128: 4 i-values/step)
#define STR      65            // bf16x8 row stride (64 + 1 pad)

typedef unsigned short u16;
typedef __attribute__((ext_vector_type(8)))  __bf16 bf16x8;
typedef __attribute__((ext_vector_type(16))) float  f32x16;

// ---------------------------------------------------------------------------
// Prep: repack fouriercoeffs (2,256,128,16) f32 -> Bpack bf16 [K/8][256][8]
// with k = i*32 + t*16 + g  (t: 0=cos, 1=sin; slot g holds harmonic g+1).
// ---------------------------------------------------------------------------
__global__ __launch_bounds__(256) void kan_prep(const float* __restrict__ C,
                                                u16* __restrict__ Bpack) {
    const int o = threadIdx.x;   // 0..255 output channel
    const int i = blockIdx.x;    // 0..127 input dim
    const int t = blockIdx.y;    // 0=cos, 1=sin
    const float* src = C + (((size_t)(t * OUT_DIM + o) * IN_DIM + i) * 16);
    bf16x8 lo = {}, hi = {};
#pragma unroll
    for (int g = 0; g < 8; ++g) {
        lo[g] = (__bf16)src[g];
        hi[g] = (__bf16)src[8 + g];
    }
    const int ko = i * 4 + t * 2;       // k>>3
    bf16x8* dst = (bf16x8*)Bpack;
    dst[(size_t)ko * OUT_DIM + o]       = lo;   // g = 0..7
    dst[(size_t)(ko + 1) * OUT_DIM + o] = hi;   // g = 8..15
}

// ---------------------------------------------------------------------------
// Fused trig + bf16 MFMA GEMM, v7: 32x32x16 MFMA (2x FLOP per fragment byte).
//  - BM=64, BK=128, 256 thr = 4 waves; wave tile 64x64 = fm2 x fn2 of 32x32.
//    A-LDS/FLOP = B-L2/FLOP = 1/64 B (both halved vs v5; B at v5's proven-
//    safe rate). MFMA floor 27.5us (32x32 pipe 4061 FLOP/cy/CU, m119) now
//    exceeds the LDS wall (~15-19us) -> MFMA-bound.
//  - 512 blocks = 2 blocks/CU = 2 waves/SIMD; latency hidden by full-kt B
//    register prefetch (16 frags, issued right after barrier, ~192 VGPR,
//    cap 256 at launch_bounds(256,2)).
//  - gen / dbuf / 1-barrier-per-kt structure v5-verbatim (proven numerics).
//  - C/D layout (verified m74/m101): col=lane&31, row=(r&3)+8*(r>>2)+4*(l>>5).
// ---------------------------------------------------------------------------
__global__ __launch_bounds__(256, 2) void kan_gemm(const float* __restrict__ x,
                                                   const u16* __restrict__ Bpack,
                                                   const float* __restrict__ bias,
                                                   float* __restrict__ out) {
    __shared__ __align__(16) u16 Asm[2][16 * STR * 8];   // 2 x 16640 B

    const int tid  = threadIdx.x;
    const int lane = tid & 63;
    const int wn   = tid >> 6;       // 0..3  col block (64 cols)
    const int la31 = lane & 31;
    const int gh   = lane >> 5;      // 0..1  k-half within a K=16 window
    const int m0   = blockIdx.x * BM;

    // trig task mapping: thread -> (row tr, i-sub til), i = kt*4 + til
    const int tr  = tid >> 2;        // 0..63
    const int til = tid & 3;         // 0..3

    f32x16 vz;
#pragma unroll
    for (int r = 0; r < 16; ++r) vz[r] = 0.f;
    f32x16 acc[2][2] = {{vz, vz}, {vz, vz}};

    const bf16x8* Bv = (const bf16x8*)Bpack;
    bf16x8* Av0 = (bf16x8*)Asm[0];
    bf16x8* Av1 = (bf16x8*)Asm[1];

    const float* xrow = x + (size_t)(m0 + tr) * IN_DIM + til;
    const int bcol = wn * 64 + la31;           // + fn*32 per fragment

    // ---- harmonic generator (v5 verbatim): 4 ds_write_b128 ----
    auto gen = [&](bf16x8* Av, float xv) {
        float s1, c1;
        __sincosf(xv, &s1, &c1);
        const float t2 = 2.f * c1;
        bf16x8 qc0 = {}, qc1 = {}, qs0 = {}, qs1 = {};
        float cp = c1, sp = s1;                    // harmonic 1
        float cc = t2 * c1 - 1.f, sc = t2 * s1;    // harmonic 2
        qc0[0] = (__bf16)cp;  qs0[0] = (__bf16)sp;
        qc0[1] = (__bf16)cc;  qs0[1] = (__bf16)sc;
#pragma unroll
        for (int g = 3; g <= 16; ++g) {            // Chebyshev: 2 FMA each
            const float cn = t2 * cc - cp;
            const float sn = t2 * sc - sp;
            cp = cc; sp = sc; cc = cn; sc = sn;
            const int idx = g - 1;                 // slot = harmonic-1
            if (idx < 8) { qc0[idx] = (__bf16)cc;      qs0[idx] = (__bf16)sc; }
            else         { qc1[idx - 8] = (__bf16)cc;  qs1[idx - 8] = (__bf16)sc; }
        }
        const int kob = til * 4;   // local ko = til*4 + t*2 + (g>>3)
        Av[(kob + 0) * STR + tr] = qc0;
        Av[(kob + 1) * STR + tr] = qc1;
        Av[(kob + 2) * STR + tr] = qs0;
        Av[(kob + 3) * STR + tr] = qs1;
    };

    // kw = iw*2 + t indexes the 8 K=16 windows of a kt; local ko(kw, gh):
    //   koL = (kw>>1)*4 + (kw&1)*2 + gh   (global: + kt*16)
    bf16x8 Bcur[8][2], Bnxt[8][2];

    // prologue: B for kt=0, gen tile 0, x for tile 1
#pragma unroll
    for (int kw = 0; kw < 8; ++kw)
#pragma unroll
        for (int fn = 0; fn < 2; ++fn)
            Bcur[kw][fn] = Bv[(size_t)((kw >> 1) * 4 + (kw & 1) * 2 + gh) * OUT_DIM
                              + bcol + fn * 32];
    float xn = xrow[4];
    gen(Av0, xrow[0]);
    __syncthreads();

    for (int kt = 0; kt < NSTEPS; ++kt) {
        bf16x8* Avc = (kt & 1) ? Av1 : Av0;
        bf16x8* Avn = (kt & 1) ? Av0 : Av1;

        // issue next-kt B loads immediately (consumed next iteration)
        const int ktn = (kt + 1) & (NSTEPS - 1);
#pragma unroll
        for (int kw = 0; kw < 8; ++kw)
#pragma unroll
            for (int fn = 0; fn < 2; ++fn)
                Bnxt[kw][fn] = Bv[(size_t)(ktn * 16 + (kw >> 1) * 4 + (kw & 1) * 2 + gh)
                                  * OUT_DIM + bcol + fn * 32];

        // generate next A tile (VALU) — interleaves with this tile's MFMAs
        if (kt + 1 < NSTEPS) {
            gen(Avn, xn);
            xn = xrow[((kt + 2) & (NSTEPS - 1)) * 4];
        }

#pragma unroll
        for (int kw = 0; kw < 8; ++kw) {
            const int koL = (kw >> 1) * 4 + (kw & 1) * 2 + gh;
            bf16x8 af[2];
#pragma unroll
            for (int fm = 0; fm < 2; ++fm)
                af[fm] = Avc[koL * STR + fm * 32 + la31];
#pragma unroll
            for (int fm = 0; fm < 2; ++fm)
#pragma unroll
                for (int fn = 0; fn < 2; ++fn)
                    acc[fm][fn] = __builtin_amdgcn_mfma_f32_32x32x16_bf16(
                        af[fm], Bcur[kw][fn], acc[fm][fn], 0, 0, 0);
        }
#pragma unroll
        for (int kw = 0; kw < 8; ++kw)
#pragma unroll
            for (int fn = 0; fn < 2; ++fn)
                Bcur[kw][fn] = Bnxt[kw][fn];
        __syncthreads();
    }

    // ---- epilogue: col=lane&31, row=(r&3)+8*(r>>2)+4*(lane>>5) ----
#pragma unroll
    for (int fn = 0; fn < 2; ++fn) {
        const int col = bcol + fn * 32;
        const float bv = bias[col];
#pragma unroll
        for (int fm = 0; fm < 2; ++fm) {
            const int rbase = m0 + fm * 32 + 4 * gh;
#pragma unroll
            for (int r = 0; r < 16; ++r) {
                const int row = rbase + (r & 3) + 8 * (r >> 2);
                out[(size_t)row * OUT_DIM + col] = acc[fm][fn][r] + bv;
            }
        }
    }
}

extern "C" void kernel_launch(void* const* d_in, const int* in_sizes, int n_in,
                              void* d_out, int out_size, void* d_ws, size_t ws_size,
                              hipStream_t stream) {
    const float* x    = (const float*)d_in[0];   // (32768, 128) f32
    const float* fc   = (const float*)d_in[1];   // (2, 256, 128, 16) f32
    const float* bias = (const float*)d_in[2];   // (1, 256) f32
    float* out        = (float*)d_out;           // (32768, 256) f32
    u16* Bpack        = (u16*)d_ws;              // 4096*256*2 B = 2 MB scratch

    kan_prep<<<dim3(IN_DIM, 2), OUT_DIM, 0, stream>>>(fc, Bpack);
    kan_gemm<<<dim3(NROWS / BM), 256, 0, stream>>>(x, Bpack, bias, out);
}